// Round 5
// baseline (68.306 us; speedup 1.0000x reference)
//
#include <hip/hip_runtime.h>

// n=4, L=8192, h=8, e=64, fp32 in/out
#define N_      4
#define L_      8192
#define H_      8
#define E_      64
#define NH_     (N_ * H_)
#define STRIDE_ (H_ * E_)          // 512 floats between rows
#define SPLIT_  32                 // s-split for phase 1
#define RPB_    (L_ / SPLIT_)      // 256 rows per p1 block
#define NCH_    (RPB_ / 16)        // 16 chunks of 16 s-rows

// ws layout (floats): pkv[1024][4096] | pks[1024][64] | kvt(bf16)[32][4096] | ksum[32][64]
#define PKV_FLOATS ((size_t)NH_ * SPLIT_ * E_ * E_)
#define PKS_FLOATS ((size_t)NH_ * SPLIT_ * E_)
#define KVT_FLOATS ((size_t)NH_ * E_ * E_ / 2)
#define PKS_OFF  PKV_FLOATS
#define KVT_OFF  (PKV_FLOATS + PKS_FLOATS)
#define KSUM_OFF (KVT_OFF + KVT_FLOATS)

typedef short bf16x8 __attribute__((ext_vector_type(8)));
typedef float f32x16 __attribute__((ext_vector_type(16)));

__device__ __forceinline__ float featmap(float x) {
    float xs = x * 0.35355339059327373f;   // * 64^-0.25
    return xs > 0.0f ? xs + 1.0f : __expf(xs);
}
__device__ __forceinline__ unsigned short f2bf(float f) {   // RNE f32->bf16
    union { float f; unsigned u; } c{f};
    unsigned r = c.u + 0x7FFFu + ((c.u >> 16) & 1u);
    return (unsigned short)(r >> 16);
}

// ---------------------------------------------------------------------------
// Phase 1: KV_partial[d][m] = sum_s kf[s,d]*v[s,m] via bf16 MFMA 32x32x16.
// 4 waves = 2x2 tiles of 32x32. NO LDS, NO barriers: A-frag (kf) and B-frag
// (v) built directly from coalesced global dword loads; per 16 s-rows a wave
// does 16 loads + featmap/pack + 1 MFMA. 1-chunk register prefetch, fully
// unrolled (all pipeline indices compile-time).
// Fragment recipe (validated by la_out in round 4): lane l holds
// A[row=l&31][k=8*(l>>5)+j], B[k=8*(l>>5)+j][col=l&31], j=0..7.
// ---------------------------------------------------------------------------
__global__ __launch_bounds__(256) void la_kv(
    const float* __restrict__ keys, const float* __restrict__ values,
    float* __restrict__ pkv, float* __restrict__ pks)
{
    const int blk = blockIdx.x;
    const int nh = blk / SPLIT_, chunk = blk % SPLIT_;
    const int n = nh / H_, h = nh % H_;
    const int t = threadIdx.x, l = t & 63;
    const int w = t >> 6, wd = w >> 1, wm = w & 1;
    const int lm = l & 31, lh = l >> 5;

    const size_t base = (size_t)n * (L_ * H_ * E_) + (size_t)h * E_;
    const int s0 = chunk * RPB_;
    // Column pointers: A reads k[.][32*wd+lm], B reads v[.][32*wm+lm].
    const float* kcol = keys   + base + (size_t)s0 * STRIDE_ + 32 * wd + lm;
    const float* vcol = values + base + (size_t)s0 * STRIDE_ + 32 * wm + lm;

    f32x16 acc = {0,0,0,0,0,0,0,0,0,0,0,0,0,0,0,0};
    float ksum = 0.f;

    float ka[2][8], va[2][8];
    #pragma unroll
    for (int j = 0; j < 8; ++j) {
        ka[0][j] = kcol[(size_t)(8 * lh + j) * STRIDE_];
        va[0][j] = vcol[(size_t)(8 * lh + j) * STRIDE_];
    }

    #pragma unroll
    for (int c = 0; c < NCH_; ++c) {
        const int cur = c & 1, nxt = cur ^ 1;      // compile-time (full unroll)
        if (c + 1 < NCH_) {
            #pragma unroll
            for (int j = 0; j < 8; ++j) {
                ka[nxt][j] = kcol[(size_t)((c + 1) * 16 + 8 * lh + j) * STRIDE_];
                va[nxt][j] = vcol[(size_t)((c + 1) * 16 + 8 * lh + j) * STRIDE_];
            }
        }
        bf16x8 af, bf;
        #pragma unroll
        for (int j = 0; j < 8; ++j) {
            const float kf = featmap(ka[cur][j]);
            ksum += kf;
            af[j] = (short)f2bf(kf);
            bf[j] = (short)f2bf(va[cur][j]);
        }
        acc = __builtin_amdgcn_mfma_f32_32x32x16_bf16(af, bf, acc, 0, 0, 0);
    }

    // C/D layout (m74/m101): col=lane&31, row=(r&3)+8*(r>>2)+4*(lane>>5)
    float* dst = pkv + (size_t)blk * (E_ * E_);
    #pragma unroll
    for (int r = 0; r < 16; ++r) {
        const int ro = (r & 3) + 8 * (r >> 2) + 4 * lh;
        dst[(32 * wd + ro) * E_ + 32 * wm + lm] = acc[r];
    }

    // ksum[d]: lane holds partial for d=32*wd+lm over its s-half; combine
    // halves, store from wm==0 waves only (wm==1 would double-count).
    ksum += __shfl_xor(ksum, 32);
    if (wm == 0 && lh == 0)
        pks[(size_t)blk * E_ + 32 * wd + lm] = ksum;
}

// ---------------------------------------------------------------------------
// Reduce: KV[d][m] = sum_c pkv; emit KV^T bf16 [m][d] + ksum f32.
// ---------------------------------------------------------------------------
__global__ __launch_bounds__(256) void la_reduce(
    const float* __restrict__ pkv, const float* __restrict__ pks,
    unsigned short* __restrict__ kvt, float* __restrict__ ksum)
{
    const int b = blockIdx.x, nh = b >> 4, sl = b & 15;
    const int e = sl * 256 + threadIdx.x;          // e = d*64 + m
    const float* src = pkv + (size_t)nh * SPLIT_ * (E_ * E_) + e;
    float s = 0.f;
    #pragma unroll
    for (int c = 0; c < SPLIT_; ++c) s += src[(size_t)c * (E_ * E_)];
    const int d = e >> 6, m = e & 63;
    kvt[(size_t)nh * (E_ * E_) + m * E_ + d] = f2bf(s);

    if (sl == 0 && threadIdx.x < E_) {
        const float* sp = pks + (size_t)nh * SPLIT_ * E_ + threadIdx.x;
        float ss = 0.f;
        #pragma unroll
        for (int c = 0; c < SPLIT_; ++c) ss += sp[c * E_];
        ksum[nh * E_ + threadIdx.x] = ss;
    }
}

// ---------------------------------------------------------------------------
// Phase 2: out[l][m] = z[l] * sum_d qf[l,d]*KV[d,m] via MFMA (unchanged).
// ---------------------------------------------------------------------------
__global__ __launch_bounds__(256) void la_out(
    const float* __restrict__ q, const unsigned short* __restrict__ kvt,
    const float* __restrict__ ksum, float* __restrict__ out)
{
    const int blk = blockIdx.x, nh = blk >> 5, tile = blk & 31;
    const int n = nh / H_, h = nh % H_;
    const int t = threadIdx.x, l = t & 63, w = t >> 6;
    const int lm = l & 31, lh = l >> 5;

    __shared__ float zbuf[4][32];

    const unsigned short* kb = kvt + (size_t)nh * (E_ * E_);
    const float* ks = ksum + nh * E_;

    bf16x8 bfr[4][2];
    float4 kr[4][2];
    #pragma unroll
    for (int st = 0; st < 4; ++st) {
        #pragma unroll
        for (int c = 0; c < 2; ++c)
            bfr[st][c] = *(const bf16x8*)&kb[(32 * c + lm) * E_ + st * 16 + 8 * lh];
        kr[st][0] = *(const float4*)&ks[st * 16 + 8 * lh];
        kr[st][1] = *(const float4*)&ks[st * 16 + 8 * lh + 4];
    }

    const size_t base = (size_t)n * (L_ * H_ * E_) + (size_t)h * E_;

    #pragma unroll
    for (int bnd = 0; bnd < 2; ++bnd) {
        const int l0 = tile * 256 + w * 64 + bnd * 32;
        const float* qp = q + base + (size_t)(l0 + lm) * STRIDE_ + 8 * lh;

        float4 qa[4], qb[4];
        #pragma unroll
        for (int st = 0; st < 4; ++st) {
            qa[st] = *(const float4*)(qp + st * 16);
            qb[st] = *(const float4*)(qp + st * 16 + 4);
        }

        float zd = 0.f;
        bf16x8 af[4];
        #pragma unroll
        for (int st = 0; st < 4; ++st) {
            const float f0 = featmap(qa[st].x), f1 = featmap(qa[st].y),
                        f2 = featmap(qa[st].z), f3 = featmap(qa[st].w);
            const float g0 = featmap(qb[st].x), g1 = featmap(qb[st].y),
                        g2 = featmap(qb[st].z), g3 = featmap(qb[st].w);
            zd += f0 * kr[st][0].x + f1 * kr[st][0].y + f2 * kr[st][0].z + f3 * kr[st][0].w
                + g0 * kr[st][1].x + g1 * kr[st][1].y + g2 * kr[st][1].z + g3 * kr[st][1].w;
            bf16x8 a;
            a[0] = (short)f2bf(f0); a[1] = (short)f2bf(f1);
            a[2] = (short)f2bf(f2); a[3] = (short)f2bf(f3);
            a[4] = (short)f2bf(g0); a[5] = (short)f2bf(g1);
            a[6] = (short)f2bf(g2); a[7] = (short)f2bf(g3);
            af[st] = a;
        }
        zd += __shfl_xor(zd, 32);
        const float z = 1.0f / (zd + 1e-6f);
        if (l < 32) zbuf[w][l] = z;
        __builtin_amdgcn_wave_barrier();

        f32x16 c0 = {0,0,0,0,0,0,0,0,0,0,0,0,0,0,0,0};
        f32x16 c1 = {0,0,0,0,0,0,0,0,0,0,0,0,0,0,0,0};
        #pragma unroll
        for (int st = 0; st < 4; ++st) {
            c0 = __builtin_amdgcn_mfma_f32_32x32x16_bf16(af[st], bfr[st][0], c0, 0, 0, 0);
            c1 = __builtin_amdgcn_mfma_f32_32x32x16_bf16(af[st], bfr[st][1], c1, 0, 0, 0);
        }

        float* op = out + base + (size_t)l0 * STRIDE_ + lm;
        #pragma unroll
        for (int r = 0; r < 16; ++r) {
            const int ro = (r & 3) + 8 * (r >> 2) + 4 * lh;
            const float zz = zbuf[w][ro];
            op[(size_t)ro * STRIDE_]      = c0[r] * zz;
            op[(size_t)ro * STRIDE_ + 32] = c1[r] * zz;
        }
        __builtin_amdgcn_wave_barrier();   // zbuf reused next band
    }
}

extern "C" void kernel_launch(void* const* d_in, const int* in_sizes, int n_in,
                              void* d_out, int out_size, void* d_ws, size_t ws_size,
                              hipStream_t stream) {
    (void)in_sizes; (void)n_in; (void)out_size; (void)ws_size;
    const float* qq = (const float*)d_in[0];
    const float* kk = (const float*)d_in[1];
    const float* vv = (const float*)d_in[2];
    float* outp = (float*)d_out;
    float* ws   = (float*)d_ws;

    float* pkv = ws;
    float* pks = ws + PKS_OFF;
    unsigned short* kvt = (unsigned short*)(ws + KVT_OFF);
    float* ksm = ws + KSUM_OFF;

    la_kv<<<NH_ * SPLIT_, 256, 0, stream>>>(kk, vv, pkv, pks);
    la_reduce<<<NH_ * 16, 256, 0, stream>>>(pkv, pks, kvt, ksm);
    la_out<<<NH_ * 32, 256, 0, stream>>>(qq, kvt, ksm, outp);
}